// Round 6
// baseline (274.351 us; speedup 1.0000x reference)
//
#include <hip/hip_runtime.h>
#include <stdint.h>

#define M_DIM 8192   // K of the Gram GEMM
#define N_DIM 4096   // output N x N

typedef __attribute__((ext_vector_type(16))) float f32x16;
typedef __attribute__((ext_vector_type(8))) short bf16x8;

__device__ __forceinline__ ushort f2bf(float x) {
  union { float f; uint32_t u; } v;
  v.f = x;
  uint32_t r = (v.u + 0x7fffu + ((v.u >> 16) & 1u)) >> 16;
  return (ushort)r;
}

__device__ __forceinline__ void gl_lds16b(const char* g, char* l) {
  __builtin_amdgcn_global_load_lds(
      (const __attribute__((address_space(1))) void*)g,
      (__attribute__((address_space(3))) void*)l, 16, 0, 0);
}

#define CFENCE asm volatile("" ::: "memory")

// ---------------- Kernel 1: A[M][N] fp32 -> At[N][M] bf16
__global__ __launch_bounds__(256) void transpose_convert(
    const float* __restrict__ A, ushort* __restrict__ At) {
  __shared__ ushort tile[64][66];
  const int bm = blockIdx.x % (M_DIM / 64);
  const int bn = blockIdx.x / (M_DIM / 64);
  const int m0 = bm * 64, n0 = bn * 64;
  const int t = threadIdx.x;
  const int tr = t >> 4;
  const int tc = (t & 15) << 2;
#pragma unroll
  for (int p = 0; p < 4; ++p) {
    const int r = p * 16 + tr;
    const float4 v = *reinterpret_cast<const float4*>(
        &A[(size_t)(m0 + r) * N_DIM + (n0 + tc)]);
    tile[tc + 0][r] = f2bf(v.x);
    tile[tc + 1][r] = f2bf(v.y);
    tile[tc + 2][r] = f2bf(v.z);
    tile[tc + 3][r] = f2bf(v.w);
  }
  __syncthreads();
#pragma unroll
  for (int p = 0; p < 4; ++p) {
    const int rn = p * 16 + tr;
    ushort4 o;
    o.x = tile[rn][tc + 0];
    o.y = tile[rn][tc + 1];
    o.z = tile[rn][tc + 2];
    o.w = tile[rn][tc + 3];
    *reinterpret_cast<ushort4*>(
        &At[(size_t)(n0 + rn) * M_DIM + (m0 + tc)]) = o;
  }
}

// ---------------- Kernel 2: 256x256 tile, BK=32, 4 LDS bufs, 32x32x16 MFMA,
// register-pipelined fragments (read S+1 during S's MFMAs), vmcnt(4)/barrier.
// LDS buf b (base b*32768): A 256rows x 64B @0, B @16384.
// Swizzle (involution): byte d -> d ^ ((d>>7)&3)<<4.
__global__ __launch_bounds__(512, 1) void gram32(
    const ushort* __restrict__ At, float* __restrict__ C) {
  __shared__ char smem[131072];

  const int bid = (int)blockIdx.x;
  const int wg = (bid & 7) * 32 + (bid >> 3);  // XCD swizzle (256 % 8 == 0)
  const int bi = wg >> 4, bj = wg & 15;

  const int t = (int)threadIdx.x;
  const int lane = t & 63, wave = t >> 6;
  const int wr = wave >> 2, wc = wave & 3;   // wave tile: rows wr*128, cols wc*64
  const int l31 = lane & 31, hi = lane >> 5;

  // ---- fragment read offsets (32x32x16): lane reads 16B at row l31+base,
  // col kk*32 | hi*16, XOR ((row>>1)&3)<<4 (row%32==l31 -> (row>>1)&3==(l31>>1)&3)
  const int cswz = ((l31 >> 1) & 3) << 4;
  const int colk0 = (hi * 16) ^ cswz;
  const int colk1 = (32 | (hi * 16)) ^ cswz;
  int adA[4][2], adB[2][2];
#pragma unroll
  for (int mb = 0; mb < 4; ++mb) {
    adA[mb][0] = (wr * 128 + mb * 32 + l31) * 64 + colk0;
    adA[mb][1] = (wr * 128 + mb * 32 + l31) * 64 + colk1;
  }
#pragma unroll
  for (int nb = 0; nb < 2; ++nb) {
    adB[nb][0] = 16384 + (wc * 64 + nb * 32 + l31) * 64 + colk0;
    adB[nb][1] = 16384 + (wc * 64 + nb * 32 + l31) * 64 + colk1;
  }

  // ---- staging (unchanged from R5): linear LDS dest, pre-swizzled global col
  const char* const Atb = (const char*)At;
  const size_t MB = (size_t)M_DIM * 2;
  const int rq = t >> 2;
  const int cs = ((t & 3) ^ ((t >> 3) & 3)) * 16;
  const char* const sA0 = Atb + (size_t)(bi * 256 + rq) * MB + cs;
  const char* const sA1 = Atb + (size_t)(bi * 256 + 128 + rq) * MB + cs;
  const char* const sB0 = Atb + (size_t)(bj * 256 + rq) * MB + cs;
  const char* const sB1 = Atb + (size_t)(bj * 256 + 128 + rq) * MB + cs;
  const int d0 = t * 16, d1 = 8192 + t * 16;

  bf16x8 fA[2][4][2], fB[2][2][2];
  f32x16 acc[4][2] = {};

  // ---- prologue: stage tiles 0,1,2; wait tile0 block-wide; read frags(0)
#pragma unroll
  for (int ss = 0; ss < 3; ++ss) {
    char* const b = smem + ss * 32768;
    const size_t ko = (size_t)ss * 64;
    gl_lds16b(sA0 + ko, b + d0);
    gl_lds16b(sA1 + ko, b + d1);
    gl_lds16b(sB0 + ko, b + 16384 + d0);
    gl_lds16b(sB1 + ko, b + 16384 + d1);
  }
  asm volatile("s_waitcnt vmcnt(8)" ::: "memory");
  __builtin_amdgcn_s_barrier();
  CFENCE;
#pragma unroll
  for (int mb = 0; mb < 4; ++mb) {
    fA[0][mb][0] = *reinterpret_cast<const bf16x8*>(smem + adA[mb][0]);
    fA[0][mb][1] = *reinterpret_cast<const bf16x8*>(smem + adA[mb][1]);
  }
#pragma unroll
  for (int nb = 0; nb < 2; ++nb) {
    fB[0][nb][0] = *reinterpret_cast<const bf16x8*>(smem + adB[nb][0]);
    fB[0][nb][1] = *reinterpret_cast<const bf16x8*>(smem + adB[nb][1]);
  }

#define ITER(S, CUR, NXT, STG, VMW, RDN) do {                                \
  if ((VMW) == 4)      asm volatile("s_waitcnt vmcnt(4)" ::: "memory");      \
  else if ((VMW) == 0) asm volatile("s_waitcnt vmcnt(0)" ::: "memory");      \
  __builtin_amdgcn_s_barrier();                                              \
  CFENCE;                                                                    \
  if (STG) {                                                                 \
    char* const sbf = smem + (((S) + 3) & 3) * 32768;                        \
    const size_t ko = (size_t)((S) + 3) * 64;                                \
    gl_lds16b(sA0 + ko, sbf + d0);                                           \
    gl_lds16b(sA1 + ko, sbf + d1);                                           \
    gl_lds16b(sB0 + ko, sbf + 16384 + d0);                                   \
    gl_lds16b(sB1 + ko, sbf + 16384 + d1);                                   \
  }                                                                          \
  if (RDN) {                                                                 \
    const char* const nb_ = smem + (((S) + 1) & 3) * 32768;                  \
    _Pragma("unroll") for (int mb = 0; mb < 4; ++mb) {                       \
      fA[NXT][mb][0] = *reinterpret_cast<const bf16x8*>(nb_ + adA[mb][0]);   \
      fA[NXT][mb][1] = *reinterpret_cast<const bf16x8*>(nb_ + adA[mb][1]);   \
    }                                                                        \
    _Pragma("unroll") for (int nb = 0; nb < 2; ++nb) {                       \
      fB[NXT][nb][0] = *reinterpret_cast<const bf16x8*>(nb_ + adB[nb][0]);   \
      fB[NXT][nb][1] = *reinterpret_cast<const bf16x8*>(nb_ + adB[nb][1]);   \
    }                                                                        \
  }                                                                          \
  _Pragma("unroll") for (int kk = 0; kk < 2; ++kk)                           \
    _Pragma("unroll") for (int mb = 0; mb < 4; ++mb)                         \
      _Pragma("unroll") for (int nb = 0; nb < 2; ++nb)                       \
        acc[mb][nb] = __builtin_amdgcn_mfma_f32_32x32x16_bf16(               \
            fA[CUR][mb][kk], fB[CUR][nb][kk], acc[mb][nb], 0, 0, 0);         \
} while (0)

  for (int s = 0; s < 252; s += 4) {
    ITER(s + 0, 0, 1, true, 4, 1);
    ITER(s + 1, 1, 0, true, 4, 1);
    ITER(s + 2, 0, 1, true, 4, 1);
    ITER(s + 3, 1, 0, true, 4, 1);
  }
  ITER(252, 0, 1, true, 4, 1);   // stages tile 255, reads frags 253
  ITER(253, 1, 0, false, 4, 1);  // reads frags 254
  ITER(254, 0, 1, false, 0, 1);  // reads frags 255
  ITER(255, 1, 0, false, -1, 0); // MFMA only

#undef ITER

  // ---- epilogue: 32x32 C/D map (m74/m101): col=lane&31,
  // row = (reg&3) + 8*(reg>>2) + 4*(lane>>5)
  const int rb = bi * 256 + wr * 128;
  const int cb = bj * 256 + wc * 64;
#pragma unroll
  for (int mb = 0; mb < 4; ++mb) {
#pragma unroll
    for (int nb = 0; nb < 2; ++nb) {
      const int c = cb + nb * 32 + l31;
#pragma unroll
      for (int rg = 0; rg < 4; ++rg) {
        const int r0 = rb + mb * 32 + rg * 8 + hi * 4;
#pragma unroll
        for (int j = 0; j < 4; ++j)
          C[(size_t)(r0 + j) * N_DIM + c] = acc[mb][nb][rg * 4 + j];
      }
    }
  }
}

extern "C" void kernel_launch(void* const* d_in, const int* in_sizes, int n_in,
                              void* d_out, int out_size, void* d_ws, size_t ws_size,
                              hipStream_t stream) {
  const float* A = (const float*)d_in[0];
  float* C = (float*)d_out;
  ushort* At = (ushort*)d_ws;  // 64 MiB

  transpose_convert<<<dim3((M_DIM / 64) * (N_DIM / 64)), 256, 0, stream>>>(A, At);
  gram32<<<dim3(16 * 16), 512, 0, stream>>>(At, C);
}

// Round 7
// 256.666 us; speedup vs baseline: 1.0689x; 1.0689x over previous
//
#include <hip/hip_runtime.h>
#include <stdint.h>

#define M_DIM 8192   // K of the Gram GEMM
#define N_DIM 4096   // output N x N

typedef __attribute__((ext_vector_type(4))) float f32x4;
typedef __attribute__((ext_vector_type(8))) short bf16x8;

__device__ __forceinline__ ushort f2bf(float x) {
  union { float f; uint32_t u; } v;
  v.f = x;
  uint32_t r = (v.u + 0x7fffu + ((v.u >> 16) & 1u)) >> 16;
  return (ushort)r;
}

__device__ __forceinline__ void gl_lds16b(const char* g, char* l) {
  __builtin_amdgcn_global_load_lds(
      (const __attribute__((address_space(1))) void*)g,
      (__attribute__((address_space(3))) void*)l, 16, 0, 0);
}

#define CFENCE asm volatile("" ::: "memory")

// ---------------- Kernel 1: A[M][N] fp32 -> At[N][M] bf16
__global__ __launch_bounds__(256) void transpose_convert(
    const float* __restrict__ A, ushort* __restrict__ At) {
  __shared__ ushort tile[64][66];
  const int bm = blockIdx.x % (M_DIM / 64);
  const int bn = blockIdx.x / (M_DIM / 64);
  const int m0 = bm * 64, n0 = bn * 64;
  const int t = threadIdx.x;
  const int tr = t >> 4;
  const int tc = (t & 15) << 2;
#pragma unroll
  for (int p = 0; p < 4; ++p) {
    const int r = p * 16 + tr;
    const float4 v = *reinterpret_cast<const float4*>(
        &A[(size_t)(m0 + r) * N_DIM + (n0 + tc)]);
    tile[tc + 0][r] = f2bf(v.x);
    tile[tc + 1][r] = f2bf(v.y);
    tile[tc + 2][r] = f2bf(v.z);
    tile[tc + 3][r] = f2bf(v.w);
  }
  __syncthreads();
#pragma unroll
  for (int p = 0; p < 4; ++p) {
    const int rn = p * 16 + tr;
    ushort4 o;
    o.x = tile[rn][tc + 0];
    o.y = tile[rn][tc + 1];
    o.z = tile[rn][tc + 2];
    o.w = tile[rn][tc + 3];
    *reinterpret_cast<ushort4*>(
        &At[(size_t)(n0 + rn) * M_DIM + (m0 + tc)]) = o;
  }
}

// ---------------- Kernel 2: R5 state + ONE change: register-pipelined
// fragment reads (read tile S+1's frags during tile S's MFMAs), 16x16 MFMA,
// R5's exact LDS layout + swizzle (byte d -> d ^ ((d>>7)&3)<<4), 4 bufs,
// one barrier + vmcnt(4) per K-tile.
__global__ __launch_bounds__(512, 1) void gram1b(
    const ushort* __restrict__ At, float* __restrict__ C) {
  __shared__ char smem[131072];

  const int bid = (int)blockIdx.x;
  const int wg = (bid & 7) * 32 + (bid >> 3);  // XCD swizzle (256 % 8 == 0)
  const int bi = wg >> 4, bj = wg & 15;

  const int t = (int)threadIdx.x;
  const int lane = t & 63, wave = t >> 6;
  const int wr = wave >> 2, wc = wave & 3;   // wave tile: rows wr*128, cols wc*64
  const int fr = lane & 15, fq = lane >> 4;

  // ---- fragment read offsets (verified conflict-free in R5)
  const int colr = (fq * 16) ^ (((fr >> 1) & 3) << 4);
  int adA[8], adB[4];
#pragma unroll
  for (int m = 0; m < 8; ++m)
    adA[m] = (wr * 128 + m * 16 + fr) * 64 + colr;
#pragma unroll
  for (int n = 0; n < 4; ++n)
    adB[n] = 16384 + (wc * 64 + n * 16 + fr) * 64 + colr;

  // ---- staging (verbatim R5): linear LDS dest, pre-swizzled global col
  const char* const Atb = (const char*)At;
  const size_t MB = (size_t)M_DIM * 2;
  const int rq = t >> 2;
  const int cs = ((t & 3) ^ ((t >> 3) & 3)) * 16;
  const char* const sA0 = Atb + (size_t)(bi * 256 + rq) * MB + cs;
  const char* const sA1 = Atb + (size_t)(bi * 256 + 128 + rq) * MB + cs;
  const char* const sB0 = Atb + (size_t)(bj * 256 + rq) * MB + cs;
  const char* const sB1 = Atb + (size_t)(bj * 256 + 128 + rq) * MB + cs;
  const int d0 = t * 16, d1 = 8192 + t * 16;

  bf16x8 fA[2][8], fB[2][4];
  f32x4 acc[8][4] = {};

  // ---- prologue: stage tiles 0,1,2; wait tile0; read frags(0) into set 0
#pragma unroll
  for (int ss = 0; ss < 3; ++ss) {
    char* const b = smem + ss * 32768;
    const size_t ko = (size_t)ss * 64;
    gl_lds16b(sA0 + ko, b + d0);
    gl_lds16b(sA1 + ko, b + d1);
    gl_lds16b(sB0 + ko, b + 16384 + d0);
    gl_lds16b(sB1 + ko, b + 16384 + d1);
  }
  asm volatile("s_waitcnt vmcnt(8)" ::: "memory");
  __builtin_amdgcn_s_barrier();
  CFENCE;
#pragma unroll
  for (int m = 0; m < 8; ++m)
    fA[0][m] = *reinterpret_cast<const bf16x8*>(smem + adA[m]);
#pragma unroll
  for (int n = 0; n < 4; ++n)
    fB[0][n] = *reinterpret_cast<const bf16x8*>(smem + adB[n]);

#define ITER(S, CUR, NXT, STG, VMW, RDN) do {                                \
  if ((VMW) == 4)      asm volatile("s_waitcnt vmcnt(4)" ::: "memory");      \
  else if ((VMW) == 0) asm volatile("s_waitcnt vmcnt(0)" ::: "memory");      \
  __builtin_amdgcn_s_barrier();                                              \
  CFENCE;                                                                    \
  if (STG) {                                                                 \
    char* const sbf = smem + (((S) + 3) & 3) * 32768;                        \
    const size_t ko = (size_t)((S) + 3) * 64;                                \
    gl_lds16b(sA0 + ko, sbf + d0);                                           \
    gl_lds16b(sA1 + ko, sbf + d1);                                           \
    gl_lds16b(sB0 + ko, sbf + 16384 + d0);                                   \
    gl_lds16b(sB1 + ko, sbf + 16384 + d1);                                   \
  }                                                                          \
  if (RDN) {                                                                 \
    const char* const nb_ = smem + (((S) + 1) & 3) * 32768;                  \
    _Pragma("unroll") for (int m = 0; m < 8; ++m)                            \
      fA[NXT][m] = *reinterpret_cast<const bf16x8*>(nb_ + adA[m]);           \
    _Pragma("unroll") for (int n = 0; n < 4; ++n)                            \
      fB[NXT][n] = *reinterpret_cast<const bf16x8*>(nb_ + adB[n]);           \
  }                                                                          \
  _Pragma("unroll") for (int m = 0; m < 8; ++m)                              \
    _Pragma("unroll") for (int n = 0; n < 4; ++n)                            \
      acc[m][n] = __builtin_amdgcn_mfma_f32_16x16x32_bf16(                   \
          fA[CUR][m], fB[CUR][n], acc[m][n], 0, 0, 0);                       \
} while (0)

  // main loop: iter S computes tile S (set S&1), reads tile S+1's frags,
  // stages tile S+3
  for (int s = 0; s < 252; s += 4) {
    ITER(s + 0, 0, 1, true, 4, 1);
    ITER(s + 1, 1, 0, true, 4, 1);
    ITER(s + 2, 0, 1, true, 4, 1);
    ITER(s + 3, 1, 0, true, 4, 1);
  }
  ITER(252, 0, 1, true, 4, 1);   // stages tile 255, reads frags 253
  ITER(253, 1, 0, false, 4, 1);  // reads frags 254
  ITER(254, 0, 1, false, 0, 1);  // reads frags 255
  ITER(255, 1, 0, false, -1, 0); // MFMA only

#undef ITER

  // ---- epilogue: C/D map col=lane&15, row=fq*4+j (verified R1-R5)
  const int rb = bi * 256 + wr * 128;
  const int cb = bj * 256 + wc * 64;
#pragma unroll
  for (int m = 0; m < 8; ++m) {
    const int r0 = rb + m * 16 + fq * 4;
#pragma unroll
    for (int n = 0; n < 4; ++n) {
      const int c = cb + n * 16 + fr;
#pragma unroll
      for (int j = 0; j < 4; ++j)
        C[(size_t)(r0 + j) * N_DIM + c] = acc[m][n][j];
    }
  }
}

extern "C" void kernel_launch(void* const* d_in, const int* in_sizes, int n_in,
                              void* d_out, int out_size, void* d_ws, size_t ws_size,
                              hipStream_t stream) {
  const float* A = (const float*)d_in[0];
  float* C = (float*)d_out;
  ushort* At = (ushort*)d_ws;  // 64 MiB

  transpose_convert<<<dim3((M_DIM / 64) * (N_DIM / 64)), 256, 0, stream>>>(A, At);
  gram1b<<<dim3(16 * 16), 512, 0, stream>>>(At, C);
}

// Round 8
// 182.642 us; speedup vs baseline: 1.5021x; 1.4053x over previous
//
#include <hip/hip_runtime.h>
#include <stdint.h>

#define M_DIM 8192   // K of the Gram GEMM
#define N_DIM 4096   // output N x N

typedef __attribute__((ext_vector_type(4))) float f32x4;
typedef __attribute__((ext_vector_type(2))) long lg2;  // 16B = 2 x i64 fp8 operands

// fp32 -> OCP e4m3 (RNE, FTZ below 2^-6, saturate to 448)
__device__ __forceinline__ unsigned char f2e4m3(float x) {
  union { float f; uint32_t u; } v;
  v.f = x;
  const uint32_t s = (v.u >> 24) & 0x80;
  const uint32_t au = v.u & 0x7fffffffu;
  if (au < 0x3c800000u) return (unsigned char)s;  // |x| < 2^-6 -> 0
  const uint32_t r = au + 0x7ffffu + ((au >> 20) & 1u);  // RNE at 3 mantissa bits
  int e = (int)(r >> 23) - 127;
  uint32_t m = (r >> 20) & 7u;
  if (e > 8 || (e == 8 && m == 7)) { e = 8; m = 6; }  // sat 448, avoid NaN
  return (unsigned char)(s | ((uint32_t)(e + 7) << 3) | m);
}

__device__ __forceinline__ void gl_lds16b(const char* g, char* l) {
  __builtin_amdgcn_global_load_lds(
      (const __attribute__((address_space(1))) void*)g,
      (__attribute__((address_space(3))) void*)l, 16, 0, 0);
}

#define CFENCE asm volatile("" ::: "memory")

// ---------------- Kernel 1: A[M][N] fp32 -> At[N][M] fp8, GEMM-ready layout.
// At row n, K-chunk kb (64 elems): logical k = kk*32 + fq*8 + e stored at byte
// (fq*16 + kk*8 + e) ^ ((n>>1)&3)<<4.  One b128 LDS read at col fq*16 then
// yields lane(fq)'s operands for BOTH K-halves; bank swizzle is pre-baked.
__global__ __launch_bounds__(256) void transpose_convert_fp8(
    const float* __restrict__ A, unsigned char* __restrict__ At) {
  __shared__ unsigned char tile[64][68];
  const int bm = blockIdx.x % (M_DIM / 64);
  const int bn = blockIdx.x / (M_DIM / 64);
  const int m0 = bm * 64, n0 = bn * 64;
  const int t = threadIdx.x;
  const int tr = t >> 4;
  const int tc = (t & 15) << 2;   // 0,4,...,60 (stays within one (kk,fq) octet)
#pragma unroll
  for (int p = 0; p < 4; ++p) {
    const int r = p * 16 + tr;
    const float4 v = *reinterpret_cast<const float4*>(
        &A[(size_t)(m0 + r) * N_DIM + (n0 + tc)]);
    tile[tc + 0][r] = f2e4m3(v.x);
    tile[tc + 1][r] = f2e4m3(v.y);
    tile[tc + 2][r] = f2e4m3(v.z);
    tile[tc + 3][r] = f2e4m3(v.w);
  }
  __syncthreads();
  const int kk = (tc >> 5) & 1, fq = (tc >> 3) & 3, e0 = tc & 7;
  const int pb = fq * 16 + kk * 8 + e0;  // multiple of 4
#pragma unroll
  for (int p = 0; p < 4; ++p) {
    const int rn = p * 16 + tr;
    const int n = n0 + rn;
    uchar4 o;
    o.x = tile[rn][tc + 0];
    o.y = tile[rn][tc + 1];
    o.z = tile[rn][tc + 2];
    o.w = tile[rn][tc + 3];
    const int rsw = ((n >> 1) & 3) << 4;
    *reinterpret_cast<uchar4*>(
        &At[(size_t)n * M_DIM + (m0 >> 6) * 64 + (pb ^ rsw)]) = o;
  }
}

// ---------------- Kernel 2: R5 schedule verbatim, fp8 dtype, K=64 per iter.
// 256x256 tile, 4 LDS bufs (A 16KB + B 16KB each), one barrier + vmcnt(8)
// per iter, swizzle byte d -> d ^ ((d>>7)&3)<<4 (0-conflict, verified R5).
__global__ __launch_bounds__(512, 1) void gram_fp8(
    const unsigned char* __restrict__ At, float* __restrict__ C) {
  __shared__ char smem[131072];

  const int bid = (int)blockIdx.x;
  const int wg = (bid & 7) * 32 + (bid >> 3);  // XCD swizzle (256 % 8 == 0)
  const int bi = wg >> 4, bj = wg & 15;

  const int t = (int)threadIdx.x;
  const int lane = t & 63, wave = t >> 6;
  const int wr = wave >> 2, wc = wave & 3;   // wave tile: rows wr*128, cols wc*64
  const int fr = lane & 15, fq = lane >> 4;

  // fragment read offsets — byte-identical addresses to R5 (0 conflicts)
  const int colr = (fq * 16) ^ (((fr >> 1) & 3) << 4);
  int adA[8], adB[4];
#pragma unroll
  for (int m = 0; m < 8; ++m)
    adA[m] = (wr * 128 + m * 16 + fr) * 64 + colr;
#pragma unroll
  for (int n = 0; n < 4; ++n)
    adB[n] = 16384 + (wc * 64 + n * 16 + fr) * 64 + colr;

  // staging: global layout is already interleaved+swizzled -> plain linear copy
  const char* const Atb = (const char*)At;
  const size_t MB = (size_t)M_DIM;   // bytes per At row (fp8)
  const int rq = t >> 2;
  const int cc = (t & 3) * 16;
  const char* const sA0 = Atb + (size_t)(bi * 256 + rq) * MB + cc;
  const char* const sA1 = Atb + (size_t)(bi * 256 + 128 + rq) * MB + cc;
  const char* const sB0 = Atb + (size_t)(bj * 256 + rq) * MB + cc;
  const char* const sB1 = Atb + (size_t)(bj * 256 + 128 + rq) * MB + cc;
  const int d0 = t * 16, d1 = 8192 + t * 16;

  f32x4 acc[8][4] = {};

  // prologue: stage K-chunks 0,1,2 into bufs 0,1,2
#pragma unroll
  for (int ss = 0; ss < 3; ++ss) {
    char* const b = smem + ss * 32768;
    const size_t ko = (size_t)ss * 64;
    gl_lds16b(sA0 + ko, b + d0);
    gl_lds16b(sA1 + ko, b + d1);
    gl_lds16b(sB0 + ko, b + 16384 + d0);
    gl_lds16b(sB1 + ko, b + 16384 + d1);
  }

#define ITER(S, STG, VMW) do {                                               \
  if ((VMW) == 8)      asm volatile("s_waitcnt vmcnt(8)" ::: "memory");      \
  else if ((VMW) == 4) asm volatile("s_waitcnt vmcnt(4)" ::: "memory");      \
  else if ((VMW) == 0) asm volatile("s_waitcnt vmcnt(0)" ::: "memory");      \
  __builtin_amdgcn_s_barrier();                                              \
  CFENCE;                                                                    \
  {                                                                          \
    const char* const bb = smem + ((S) & 3) * 32768;                         \
    lg2 a[8], b[4];                                                          \
    _Pragma("unroll") for (int m = 0; m < 8; ++m)                            \
      a[m] = *reinterpret_cast<const lg2*>(bb + adA[m]);                     \
    _Pragma("unroll") for (int n = 0; n < 4; ++n)                            \
      b[n] = *reinterpret_cast<const lg2*>(bb + adB[n]);                     \
    if (STG) {                                                               \
      char* const sbf = smem + (((S) + 3) & 3) * 32768;                      \
      const size_t ko = (size_t)((S) + 3) * 64;                              \
      gl_lds16b(sA0 + ko, sbf + d0);                                         \
      gl_lds16b(sA1 + ko, sbf + d1);                                         \
      gl_lds16b(sB0 + ko, sbf + 16384 + d0);                                 \
      gl_lds16b(sB1 + ko, sbf + 16384 + d1);                                 \
    }                                                                        \
    _Pragma("unroll") for (int m = 0; m < 8; ++m)                            \
      _Pragma("unroll") for (int n = 0; n < 4; ++n) {                        \
        acc[m][n] = __builtin_amdgcn_mfma_f32_16x16x32_fp8_fp8(              \
            a[m].x, b[n].x, acc[m][n], 0, 0, 0);                             \
        acc[m][n] = __builtin_amdgcn_mfma_f32_16x16x32_fp8_fp8(              \
            a[m].y, b[n].y, acc[m][n], 0, 0, 0);                             \
      }                                                                      \
  }                                                                          \
} while (0)

  // 128 K-chunks of 64; stage chunk S+3 in iters 0..124
  for (int s = 0; s < 124; s += 4) {
    ITER(s + 0, true, 8);
    ITER(s + 1, true, 8);
    ITER(s + 2, true, 8);
    ITER(s + 3, true, 8);
  }
  ITER(124, true, 8);    // stages chunk 127 (all 512 loads issued)
  ITER(125, false, 8);
  ITER(126, false, 4);
  ITER(127, false, 0);

#undef ITER

  // epilogue: C/D map col=lane&15, row=fq*4+j (verified R1-R7)
  const int rb = bi * 256 + wr * 128;
  const int cb = bj * 256 + wc * 64;
#pragma unroll
  for (int m = 0; m < 8; ++m) {
    const int r0 = rb + m * 16 + fq * 4;
#pragma unroll
    for (int n = 0; n < 4; ++n) {
      const int c = cb + n * 16 + fr;
#pragma unroll
      for (int j = 0; j < 4; ++j)
        C[(size_t)(r0 + j) * N_DIM + c] = acc[m][n][j];
    }
  }
}

extern "C" void kernel_launch(void* const* d_in, const int* in_sizes, int n_in,
                              void* d_out, int out_size, void* d_ws, size_t ws_size,
                              hipStream_t stream) {
  const float* A = (const float*)d_in[0];
  float* C = (float*)d_out;
  unsigned char* At = (unsigned char*)d_ws;  // 4096*8192 = 32 MiB

  transpose_convert_fp8<<<dim3((M_DIM / 64) * (N_DIM / 64)), 256, 0, stream>>>(A, At);
  gram_fp8<<<dim3(16 * 16), 512, 0, stream>>>(At, C);
}

// Round 9
// 149.785 us; speedup vs baseline: 1.8316x; 1.2194x over previous
//
#include <hip/hip_runtime.h>
#include <stdint.h>

#define M_DIM 8192   // K of the Gram GEMM
#define N_DIM 4096   // output N x N

typedef __attribute__((ext_vector_type(4))) int i32x4;
typedef __attribute__((ext_vector_type(8))) int i32x8;
typedef __attribute__((ext_vector_type(16))) float f32x16;

// fp32 -> OCP e4m3 (RNE, FTZ below 2^-6, saturate to 448)
__device__ __forceinline__ unsigned char f2e4m3(float x) {
  union { float f; uint32_t u; } v;
  v.f = x;
  const uint32_t s = (v.u >> 24) & 0x80;
  const uint32_t au = v.u & 0x7fffffffu;
  if (au < 0x3c800000u) return (unsigned char)s;  // |x| < 2^-6 -> 0
  const uint32_t r = au + 0x7ffffu + ((au >> 20) & 1u);  // RNE at 3 mantissa bits
  int e = (int)(r >> 23) - 127;
  uint32_t m = (r >> 20) & 7u;
  if (e > 8 || (e == 8 && m == 7)) { e = 8; m = 6; }  // sat 448, avoid NaN
  return (unsigned char)(s | ((uint32_t)(e + 7) << 3) | m);
}

__device__ __forceinline__ void gl_lds16b(const char* g, char* l) {
  __builtin_amdgcn_global_load_lds(
      (const __attribute__((address_space(1))) void*)g,
      (__attribute__((address_space(3))) void*)l, 16, 0, 0);
}

#define CFENCE asm volatile("" ::: "memory")

// ---------------- Kernel 1: A[M][N] fp32 -> At[N][M] fp8, PLAIN LINEAR rows.
__global__ __launch_bounds__(256) void transpose_convert_fp8(
    const float* __restrict__ A, unsigned char* __restrict__ At) {
  __shared__ unsigned char tile[64][68];
  const int bm = blockIdx.x % (M_DIM / 64);
  const int bn = blockIdx.x / (M_DIM / 64);
  const int m0 = bm * 64, n0 = bn * 64;
  const int t = threadIdx.x;
  const int tr = t >> 4;
  const int tc = (t & 15) << 2;
#pragma unroll
  for (int p = 0; p < 4; ++p) {
    const int r = p * 16 + tr;
    const float4 v = *reinterpret_cast<const float4*>(
        &A[(size_t)(m0 + r) * N_DIM + (n0 + tc)]);
    tile[tc + 0][r] = f2e4m3(v.x);
    tile[tc + 1][r] = f2e4m3(v.y);
    tile[tc + 2][r] = f2e4m3(v.z);
    tile[tc + 3][r] = f2e4m3(v.w);
  }
  __syncthreads();
#pragma unroll
  for (int p = 0; p < 4; ++p) {
    const int rn = p * 16 + tr;
    uchar4 o;
    o.x = tile[rn][tc + 0];
    o.y = tile[rn][tc + 1];
    o.z = tile[rn][tc + 2];
    o.w = tile[rn][tc + 3];
    *reinterpret_cast<uchar4*>(
        &At[(size_t)(n0 + rn) * M_DIM + (m0 + tc)]) = o;
  }
}

// ---------------- Kernel 2: R8 schedule verbatim; core = MX-scaled
// mfma_scale_f32_32x32x64_f8f6f4 with unit scales (0x7F = 2^0, exact).
// 4 LDS bufs of 32KB (A 256x64B @0, B @16384), stage chunk S+3, vmcnt(8),
// one barrier/iter. Swizzle (involution): byte d -> d ^ ((d>>7)&3)<<4.
// Lane (l31,hi) reads 32 contiguous k-bytes: 2 x b128 at cols (hi*32)^sw,
// (hi*32+16)^sw, rows base+l31 -> 8 lanes per 4-bank group (conflict-free,
// same algebra as R5's verified-zero pattern).
__global__ __launch_bounds__(512, 1) void gram_fp8s(
    const unsigned char* __restrict__ At, float* __restrict__ C) {
  __shared__ char smem[131072];

  const int bid = (int)blockIdx.x;
  const int wg = (bid & 7) * 32 + (bid >> 3);  // XCD swizzle (256 % 8 == 0)
  const int bi = wg >> 4, bj = wg & 15;

  const int t = (int)threadIdx.x;
  const int lane = t & 63, wave = t >> 6;
  const int wr = wave >> 2, wc = wave & 3;   // wave tile: rows wr*128, cols wc*64
  const int l31 = lane & 31, hi = lane >> 5;

  // fragment read addresses (two per operand block: cols c0, c0^16)
  const int sw = ((l31 >> 1) & 3) << 4;
  const int c0 = (hi * 32) ^ sw;
  const int c1 = (hi * 32 + 16) ^ sw;
  int adA0[4], adA1[4], adB0[2], adB1[2];
#pragma unroll
  for (int mb = 0; mb < 4; ++mb) {
    const int row = wr * 128 + mb * 32 + l31;
    adA0[mb] = row * 64 + c0;
    adA1[mb] = row * 64 + c1;
  }
#pragma unroll
  for (int nb = 0; nb < 2; ++nb) {
    const int row = wc * 64 + nb * 32 + l31;
    adB0[nb] = 16384 + row * 64 + c0;
    adB1[nb] = 16384 + row * 64 + c1;
  }

  // staging (R5 algebra, 1B elems): linear LDS dest, pre-swizzled source col
  const char* const Atb = (const char*)At;
  const size_t MB = (size_t)M_DIM;   // bytes per At row (fp8)
  const int rq = t >> 2;
  const int cs = ((t & 3) ^ ((t >> 3) & 3)) * 16;
  const char* const sA0 = Atb + (size_t)(bi * 256 + rq) * MB + cs;
  const char* const sA1 = Atb + (size_t)(bi * 256 + 128 + rq) * MB + cs;
  const char* const sB0 = Atb + (size_t)(bj * 256 + rq) * MB + cs;
  const char* const sB1 = Atb + (size_t)(bj * 256 + 128 + rq) * MB + cs;
  const int d0 = t * 16, d1 = 8192 + t * 16;

  f32x16 acc[4][2] = {};

  // prologue: stage K-chunks 0,1,2 into bufs 0,1,2
#pragma unroll
  for (int ss = 0; ss < 3; ++ss) {
    char* const b = smem + ss * 32768;
    const size_t ko = (size_t)ss * 64;
    gl_lds16b(sA0 + ko, b + d0);
    gl_lds16b(sA1 + ko, b + d1);
    gl_lds16b(sB0 + ko, b + 16384 + d0);
    gl_lds16b(sB1 + ko, b + 16384 + d1);
  }

#define ITER(S, STG, VMW) do {                                               \
  if ((VMW) == 8)      asm volatile("s_waitcnt vmcnt(8)" ::: "memory");      \
  else if ((VMW) == 4) asm volatile("s_waitcnt vmcnt(4)" ::: "memory");      \
  else if ((VMW) == 0) asm volatile("s_waitcnt vmcnt(0)" ::: "memory");      \
  __builtin_amdgcn_s_barrier();                                              \
  CFENCE;                                                                    \
  {                                                                          \
    const char* const bb = smem + ((S) & 3) * 32768;                         \
    if (STG) {                                                               \
      char* const sbf = smem + (((S) + 3) & 3) * 32768;                      \
      const size_t ko = (size_t)((S) + 3) * 64;                              \
      gl_lds16b(sA0 + ko, sbf + d0);                                         \
      gl_lds16b(sA1 + ko, sbf + d1);                                         \
      gl_lds16b(sB0 + ko, sbf + 16384 + d0);                                 \
      gl_lds16b(sB1 + ko, sbf + 16384 + d1);                                 \
    }                                                                        \
    i32x8 bv[2];                                                             \
    _Pragma("unroll") for (int nb = 0; nb < 2; ++nb) {                       \
      const i32x4 blo = *reinterpret_cast<const i32x4*>(bb + adB0[nb]);      \
      const i32x4 bhi = *reinterpret_cast<const i32x4*>(bb + adB1[nb]);      \
      bv[nb] = __builtin_shufflevector(blo, bhi, 0, 1, 2, 3, 4, 5, 6, 7);    \
    }                                                                        \
    _Pragma("unroll") for (int mb = 0; mb < 4; ++mb) {                       \
      const i32x4 alo = *reinterpret_cast<const i32x4*>(bb + adA0[mb]);      \
      const i32x4 ahi = *reinterpret_cast<const i32x4*>(bb + adA1[mb]);      \
      const i32x8 av = __builtin_shufflevector(alo, ahi, 0, 1, 2, 3, 4, 5, 6, 7); \
      _Pragma("unroll") for (int nb = 0; nb < 2; ++nb)                       \
        acc[mb][nb] = __builtin_amdgcn_mfma_scale_f32_32x32x64_f8f6f4(       \
            av, bv[nb], acc[mb][nb], 0, 0,                                   \
            0, 0x7F7F7F7F, 0, 0x7F7F7F7F);                                   \
    }                                                                        \
  }                                                                          \
} while (0)

  // 128 K-chunks of 64; stage chunk S+3 in iters 0..124
  for (int s = 0; s < 124; s += 4) {
    ITER(s + 0, true, 8);
    ITER(s + 1, true, 8);
    ITER(s + 2, true, 8);
    ITER(s + 3, true, 8);
  }
  ITER(124, true, 8);    // stages chunk 127
  ITER(125, false, 8);
  ITER(126, false, 4);
  ITER(127, false, 0);

#undef ITER

  // epilogue: 32x32 C/D map (on-device verified in R6):
  // col = lane&31, row = (reg&3) + 8*(reg>>2) + 4*(lane>>5)
  const int rb = bi * 256 + wr * 128;
  const int cb = bj * 256 + wc * 64;
#pragma unroll
  for (int mb = 0; mb < 4; ++mb) {
#pragma unroll
    for (int nb = 0; nb < 2; ++nb) {
      const int c = cb + nb * 32 + l31;
#pragma unroll
      for (int rg = 0; rg < 4; ++rg) {
        const int r0 = rb + mb * 32 + rg * 8 + hi * 4;
#pragma unroll
        for (int j = 0; j < 4; ++j)
          C[(size_t)(r0 + j) * N_DIM + c] = acc[mb][nb][rg * 4 + j];
      }
    }
  }
}

extern "C" void kernel_launch(void* const* d_in, const int* in_sizes, int n_in,
                              void* d_out, int out_size, void* d_ws, size_t ws_size,
                              hipStream_t stream) {
  const float* A = (const float*)d_in[0];
  float* C = (float*)d_out;
  unsigned char* At = (unsigned char*)d_ws;  // 4096*8192 = 32 MiB

  transpose_convert_fp8<<<dim3((M_DIM / 64) * (N_DIM / 64)), 256, 0, stream>>>(A, At);
  gram_fp8s<<<dim3(16 * 16), 512, 0, stream>>>(At, C);
}